// Round 6
// baseline (293.947 us; speedup 1.0000x reference)
//
#include <hip/hip_runtime.h>

// ---------------------------------------------------------------------------
// MaskedMultiHeadAttention: B=2, T=2048, E=1024, H=16, D=64, WINDOW=256
//
// R6: GEMM K-loop restructured to global->VGPR->LDS staging (loads for tile
// k+1 issued before the compute phase of tile k -> barrier no longer drains
// fresh loads). Inline per-wave dtype detection (no detect kernel, no flag
// dependency); canon is a no-op for bf16 inputs; 5 launches total.
// ---------------------------------------------------------------------------

typedef __bf16 bf16_t;
typedef bf16_t bf16x8 __attribute__((ext_vector_type(8)));
typedef bf16_t bf16x4 __attribute__((ext_vector_type(4)));
typedef float  floatx4 __attribute__((ext_vector_type(4)));

#define SEQ_T   2048
#define NHEAD   16
#define HDIM    64
#define EMB     1024
#define WIN     256
#define SCALE_F 0.125f

// ---------------------------------------------------------------------------
// Wave-uniform dtype detect: all waves read the same 1 KB of hidden (256
// words). bf16 data -> low-16 exponent clustered near 127 (~99% in
// [100,150]); fp32 -> mantissa noise (~20%). Deterministic across blocks.
// ---------------------------------------------------------------------------
__device__ __forceinline__ int detect_bf16(const uint4* __restrict__ det)
{
    const int lane = threadIdx.x & 63;
    const uint4 v = det[lane];
    int c = 0;
    #pragma unroll
    for (int e = 0; e < 4; ++e) {
        const unsigned int ex = ((&v.x)[e] >> 7) & 0xffu;
        c += (ex >= 100u && ex <= 150u) ? 1 : 0;
    }
    #pragma unroll
    for (int m = 32; m >= 1; m >>= 1) c += __shfl_xor(c, m, 64);
    return (c * 2 > 256) ? 1 : 0;
}

// ---------------------------------------------------------------------------
// canon_all: only does work when inputs are fp32 (flag==0).
// blocks 0..4095: hidden -> Hc; 4096..4098: b_attn; 4099: b_proj.
// ---------------------------------------------------------------------------
__global__ __launch_bounds__(256) void canon_all(
    const void* __restrict__ hidden, bf16_t* __restrict__ Hc,
    const void* __restrict__ ba, bf16_t* __restrict__ bba,
    const void* __restrict__ bp, bf16_t* __restrict__ bbp)
{
    if (detect_bf16((const uint4*)hidden)) return;
    const int blk = blockIdx.x;
    const float* src;
    bf16_t* dst;
    int base;
    if (blk < 4096)      { src = (const float*)hidden; dst = Hc;  base = blk * 1024; }
    else if (blk < 4099) { src = (const float*)ba;     dst = bba; base = (blk - 4096) * 1024; }
    else                 { src = (const float*)bp;     dst = bbp; base = 0; }
    const int i4 = base + threadIdx.x * 4;
    const float4 x = *(const float4*)(src + i4);
    bf16x4 v;
    v[0] = (bf16_t)x.x; v[1] = (bf16_t)x.y;
    v[2] = (bf16_t)x.z; v[3] = (bf16_t)x.w;
    *(bf16x4*)(dst + i4) = v;
}

// ---------------------------------------------------------------------------
// Both weight transposes in one launch. blocks 0..767: w_attn (N=3072);
// 768..1023: w_proj (N=1024). Wt[n][k] = (bf16)W[k][n].
// ---------------------------------------------------------------------------
__global__ __launch_bounds__(256) void transpose_both(
    const void* __restrict__ wA, bf16_t* __restrict__ WtA,
    const void* __restrict__ wP, bf16_t* __restrict__ WtP,
    const uint4* __restrict__ det)
{
    __shared__ __align__(16) bf16_t tile[64][68];
    const int f = detect_bf16(det);
    int id = blockIdx.x;
    const void* W; bf16_t* Wt; int N, bx, by;
    if (id < 768) { W = wA; Wt = WtA; N = 3072; bx = id % 48; by = id / 48; }
    else { id -= 768; W = wP; Wt = WtP; N = 1024; bx = id % 16; by = id / 16; }
    const int K = 1024;
    const int n0 = bx * 64;
    const int k0 = by * 64;
    const int tx = threadIdx.x & 15;
    const int ty = threadIdx.x >> 4;

    #pragma unroll
    for (int r = ty; r < 64; r += 16) {
        bf16x4 v;
        const size_t base = (size_t)(k0 + r) * N + n0 + tx * 4;
        if (f) {
            v = *(const bf16x4*)((const bf16_t*)W + base);
        } else {
            const float4 x = *(const float4*)((const float*)W + base);
            v[0] = (bf16_t)x.x; v[1] = (bf16_t)x.y;
            v[2] = (bf16_t)x.z; v[3] = (bf16_t)x.w;
        }
        *(bf16x4*)&tile[r][tx * 4] = v;
    }
    __syncthreads();
    #pragma unroll
    for (int r = ty; r < 64; r += 16) {
        bf16x4 v;
        v[0] = tile[tx * 4 + 0][r];
        v[1] = tile[tx * 4 + 1][r];
        v[2] = tile[tx * 4 + 2][r];
        v[3] = tile[tx * 4 + 3][r];
        *(bf16x4*)(Wt + (size_t)(n0 + r) * K + k0 + tx * 4) = v;
    }
}

// ---------------------------------------------------------------------------
// C[M][N] = A[M][K] @ Bt[N][K]^T + bias[N]   (bf16 in, fp32 accumulate)
// R6 staging: tile k+1 -> VGPRs via coalesced global_load_dwordx4 issued
// BEFORE tile k's compute; tile k VGPRs -> LDS via swizzled ds_write_b128
// (stored chunk s = g ^ (row&7), row stride 128 B; identical mapping to the
// R5 conflict-free layout, so fragment reads are unchanged).
// A/bias selected device-side by the inline dtype flag.
// ---------------------------------------------------------------------------
template<int BNt>
__global__ __launch_bounds__(256) void gemm_bt_bias(
    const bf16_t* __restrict__ Abf,   // used when flag==1 (bf16 input)
    const bf16_t* __restrict__ Aalt,  // used when flag==0 (canonicalized)
    const bf16_t* __restrict__ Bt,
    const bf16_t* __restrict__ biasbf,
    const bf16_t* __restrict__ biasalt,
    void* __restrict__ C,
    int M, int N, int K,
    int force_bf16, const uint4* __restrict__ det)
{
    constexpr int BMt = 128;
    constexpr int NF  = BNt / 32;     // n-frags per wave (wave tile = 64 x BNt/2)
    constexpr int NB  = BNt / 32;     // B staging chunks per thread
    __shared__ __align__(16) bf16_t As[BMt * 64];   // 16 KB
    __shared__ __align__(16) bf16_t Bs[BNt * 64];   // 16 or 8 KB

    const int flag = detect_bf16(det);
    const bf16_t* A    = flag ? Abf    : Aalt;
    const bf16_t* bias = flag ? biasbf : biasalt;
    const int obf = force_bf16 | flag;

    const int tid  = threadIdx.x;
    const int wave = tid >> 6;
    const int lane = tid & 63;
    const int quad = lane >> 4;
    const int n16  = lane & 15;
    const int m0 = blockIdx.y * BMt;
    const int n0 = blockIdx.x * BNt;
    const int wm = (wave >> 1) * 64;
    const int wn = (wave & 1) * (BNt / 2);

    floatx4 acc[4][NF] = {};

    uint4 rA[4], rB[NB];

    // A: thread t covers row t>>1, 64 contiguous bytes at col (t&1)*64 elems
    const int arow = tid >> 1;
    const int acol = (tid & 1) * 32;          // elements (32 elems = 64 B)
    // B: BNt=128 same as A; BNt=64: row t>>2, 32 B at (t&3)*16 elems
    const int brow = (BNt == 128) ? (tid >> 1) : (tid >> 2);
    const int bcol = (BNt == 128) ? ((tid & 1) * 32) : ((tid & 3) * 16);

    auto loadA = [&](int kk) {
        const bf16_t* g = A + (size_t)(m0 + arow) * K + kk + acol;
        #pragma unroll
        for (int i = 0; i < 4; ++i) rA[i] = *(const uint4*)(g + i * 8);
    };
    auto loadB = [&](int kk) {
        const bf16_t* g = Bt + (size_t)(n0 + brow) * K + kk + bcol;
        #pragma unroll
        for (int i = 0; i < NB; ++i) rB[i] = *(const uint4*)(g + i * 8);
    };
    auto storeA = [&]() {
        #pragma unroll
        for (int i = 0; i < 4; ++i) {
            const int g = (acol >> 3) + i;            // global chunk 0..7
            const int s = g ^ (arow & 7);             // swizzled slot
            *(uint4*)(As + arow * 64 + s * 8) = rA[i];
        }
    };
    auto storeB = [&]() {
        #pragma unroll
        for (int i = 0; i < NB; ++i) {
            const int g = (bcol >> 3) + i;
            const int s = g ^ (brow & 7);
            *(uint4*)(Bs + brow * 64 + s * 8) = rB[i];
        }
    };

    loadA(0); loadB(0);

    for (int k0 = 0; k0 < K; k0 += 64) {
        __syncthreads();                  // LDS free (prev compute done)
        storeA(); storeB();               // waits on tile-k loads (in flight ~1 iter)
        if (k0 + 64 < K) { loadA(k0 + 64); loadB(k0 + 64); }  // fly during compute
        __syncthreads();                  // ds_writes visible

        #pragma unroll
        for (int s = 0; s < 2; ++s) {
            const int ch = (((4 * s + quad) ^ (n16 & 7)) * 8);
            const bf16_t* pa = As + (wm + n16) * 64 + ch;
            const bf16_t* pb = Bs + (wn + n16) * 64 + ch;
            bf16x8 af[4], bfr[NF];
            #pragma unroll
            for (int ff = 0; ff < 4; ++ff)
                af[ff] = *(const bf16x8*)(pa + ff * 16 * 64);
            #pragma unroll
            for (int ff = 0; ff < NF; ++ff)
                bfr[ff] = *(const bf16x8*)(pb + ff * 16 * 64);
            #pragma unroll
            for (int mf = 0; mf < 4; ++mf)
                #pragma unroll
                for (int nf = 0; nf < NF; ++nf)
                    acc[mf][nf] = __builtin_amdgcn_mfma_f32_16x16x32_bf16(
                        af[mf], bfr[nf], acc[mf][nf], 0, 0, 0);
        }
    }

    const int col   = n0 + wn + n16;
    const int rbase = m0 + wm + quad * 4;
    #pragma unroll
    for (int nf = 0; nf < NF; ++nf) {
        const float bv = (float)bias[col + nf * 16];
        #pragma unroll
        for (int mf = 0; mf < 4; ++mf) {
            #pragma unroll
            for (int r = 0; r < 4; ++r) {
                const size_t idx =
                    (size_t)(rbase + mf * 16 + r) * N + col + nf * 16;
                const float val = acc[mf][nf][r] + bv;
                if (obf) ((bf16_t*)C)[idx] = (bf16_t)val;
                else     ((float*)C)[idx]  = val;
            }
        }
    }
}

// ---------------------------------------------------------------------------
// MFMA flash attention (verified R3, unchanged). Block = (b,h,64-query tile).
// ---------------------------------------------------------------------------
#define CW   160
#define VT_S 168
#define P_S  168

__global__ __launch_bounds__(256) void attn_mfma(
    const bf16_t* __restrict__ qkv,
    bf16_t* __restrict__ attn_out)
{
    __shared__ __align__(16) bf16_t Ks[CW * 64];       // 20480 B
    __shared__ __align__(16) bf16_t Vt[64 * VT_S];     // 21504 B
    __shared__ __align__(16) bf16_t Pst[4][16 * P_S];  // 21504 B

    const int tid  = threadIdx.x;
    const int wave = tid >> 6;
    const int lane = tid & 63;
    const int quad = lane >> 4;
    const int n16  = lane & 15;

    const int i0 = blockIdx.x * 64;
    const int h  = blockIdx.y;
    const int b  = blockIdx.z;
    const size_t rowbase = (size_t)b * SEQ_T;
    const int kbase  = i0 - 256;
    const int iw     = 16 * wave;
    const int climit = 256 - i0;

    const bf16_t* Qg = qkv + (rowbase + i0 + iw + n16) * (3 * EMB) + h * HDIM;
    bf16x8 qf[2];
    qf[0] = *(const bf16x8*)(Qg + quad * 8);
    qf[1] = *(const bf16x8*)(Qg + 32 + quad * 8);

    floatx4 Oac[4] = {};
    float m_run[4], l_run[4];
    #pragma unroll
    for (int rr = 0; rr < 4; ++rr) { m_run[rr] = -3.0e38f; l_run[rr] = 0.f; }

    for (int hc = 0; hc < 2; ++hc) {
        const int cbase = hc * CW;

        bf16x8 vreg[5];
        #pragma unroll
        for (int t = 0; t < 5; ++t) {
            const int idx = tid + 256 * t;
            const int lc  = idx >> 3;
            const int d0  = (idx & 7) * 8;
            int j = kbase + cbase + lc; if (j < 0) j = 0;
            vreg[t] = *(const bf16x8*)(qkv + (rowbase + j) * (3 * EMB)
                                       + 2 * EMB + h * HDIM + d0);
        }

        __syncthreads();

        #pragma unroll
        for (int t = 0; t < 5; ++t) {
            const int lc0 = wave * 40 + t * 8;
            const int lcL = lc0 + (lane >> 3);
            int j = kbase + cbase + lcL; if (j < 0) j = 0;
            const int g = (lane & 7) ^ (lcL & 7);
            const bf16_t* src = qkv + (rowbase + j) * (3 * EMB)
                                + EMB + h * HDIM + g * 8;
            __builtin_amdgcn_global_load_lds(
                (const __attribute__((address_space(1))) void*)src,
                (__attribute__((address_space(3))) void*)(Ks + lc0 * 64),
                16, 0, 0);
        }

        #pragma unroll
        for (int t = 0; t < 5; ++t) {
            const int idx = tid + 256 * t;
            const int lc  = idx >> 3;
            const int d0  = (idx & 7) * 8;
            #pragma unroll
            for (int e = 0; e < 8; ++e)
                Vt[(d0 + e) * VT_S + lc] = vreg[t][e];
        }

        __syncthreads();

        floatx4 sc[10];
        #pragma unroll
        for (int tt = 0; tt < 10; ++tt) {
            sc[tt] = (floatx4){0.f, 0.f, 0.f, 0.f};
            #pragma unroll
            for (int s2 = 0; s2 < 2; ++s2) {
                const int lc = 16 * tt + n16;
                const int ch = (4 * s2 + quad) ^ (lc & 7);
                const bf16x8 kf = *(const bf16x8*)(Ks + lc * 64 + ch * 8);
                sc[tt] = __builtin_amdgcn_mfma_f32_16x16x32_bf16(
                    qf[s2], kf, sc[tt], 0, 0, 0);
            }
        }

        #pragma unroll
        for (int tt = 0; tt < 10; ++tt) {
            const int c  = cbase + 16 * tt + n16;
            const int cw = c - iw;
            #pragma unroll
            for (int rr = 0; rr < 4; ++rr) {
                const int r = quad * 4 + rr;
                const bool valid = (cw > r) && (cw <= r + 256) && (c >= climit);
                sc[tt][rr] = valid ? sc[tt][rr] * SCALE_F : -3.0e38f;
            }
        }

        float cm[4];
        #pragma unroll
        for (int rr = 0; rr < 4; ++rr) {
            cm[rr] = -3.0e38f;
            #pragma unroll
            for (int tt = 0; tt < 10; ++tt) cm[rr] = fmaxf(cm[rr], sc[tt][rr]);
            #pragma unroll
            for (int m = 8; m >= 1; m >>= 1)
                cm[rr] = fmaxf(cm[rr], __shfl_xor(cm[rr], m, 64));
        }

        #pragma unroll
        for (int rr = 0; rr < 4; ++rr) {
            const float mnew  = fmaxf(m_run[rr], cm[rr]);
            const float alpha = __expf(m_run[rr] - mnew);
            m_run[rr] = mnew;
            l_run[rr] *= alpha;
            #pragma unroll
            for (int nt = 0; nt < 4; ++nt) Oac[nt][rr] *= alpha;
        }

        float psum[4] = {0.f, 0.f, 0.f, 0.f};
        #pragma unroll
        for (int tt = 0; tt < 10; ++tt) {
            #pragma unroll
            for (int rr = 0; rr < 4; ++rr) {
                const float s = sc[tt][rr];
                const float e = (s > -1.0e38f) ? __expf(s - m_run[rr]) : 0.f;
                psum[rr] += e;
                Pst[wave][(quad * 4 + rr) * P_S + 16 * tt + n16] = (bf16_t)e;
            }
        }
        #pragma unroll
        for (int rr = 0; rr < 4; ++rr) {
            #pragma unroll
            for (int m = 8; m >= 1; m >>= 1)
                psum[rr] += __shfl_xor(psum[rr], m, 64);
            l_run[rr] += psum[rr];
        }

        __syncthreads();

        #pragma unroll
        for (int ks = 0; ks < 5; ++ks) {
            const bf16x8 paf = *(const bf16x8*)(
                &Pst[wave][n16 * P_S + ks * 32 + quad * 8]);
            #pragma unroll
            for (int nt = 0; nt < 4; ++nt) {
                const bf16x8 vbf = *(const bf16x8*)(
                    Vt + (nt * 16 + n16) * VT_S + ks * 32 + quad * 8);
                Oac[nt] = __builtin_amdgcn_mfma_f32_16x16x32_bf16(
                    paf, vbf, Oac[nt], 0, 0, 0);
            }
        }
    }

    #pragma unroll
    for (int rr = 0; rr < 4; ++rr) {
        const float rden = 1.0f / l_run[rr];
        const size_t row = rowbase + i0 + iw + quad * 4 + rr;
        #pragma unroll
        for (int nt = 0; nt < 4; ++nt) {
            attn_out[row * EMB + h * HDIM + nt * 16 + n16] =
                (bf16_t)(Oac[nt][rr] * rden);
        }
    }
}

// ---------------------------------------------------------------------------
extern "C" void kernel_launch(void* const* d_in, const int* in_sizes, int n_in,
                              void* d_out, int out_size, void* d_ws, size_t ws_size,
                              hipStream_t stream)
{
    const void* hidden = d_in[0];
    const void* w_attn = d_in[1];
    const void* b_attn = d_in[2];
    const void* w_proj = d_in[3];
    const void* b_proj = d_in[4];

    char* ws = (char*)d_ws;
    bf16_t* Wt_attn = (bf16_t*)(ws);                       // [3072][1024]
    bf16_t* Wt_proj = (bf16_t*)(ws + (6u << 20));          // [1024][1024]
    bf16_t* qkv     = (bf16_t*)(ws + (8u << 20));          // [4096][3072]
    bf16_t* attn_o  = (bf16_t*)(ws + (32u << 20));         // [4096][1024]
    bf16_t* Hc      = (bf16_t*)(ws + (40u << 20));         // [4096][1024]
    bf16_t* bb_attn = (bf16_t*)(ws + (48u << 20));
    bf16_t* bb_proj = (bf16_t*)(ws + (48u << 20) + 8192);

    const uint4* det = (const uint4*)hidden;

    canon_all<<<4100, 256, 0, stream>>>(hidden, Hc, b_attn, bb_attn,
                                        b_proj, bb_proj);

    transpose_both<<<1024, 256, 0, stream>>>(w_attn, Wt_attn,
                                             w_proj, Wt_proj, det);

    gemm_bt_bias<128><<<dim3(3072 / 128, 4096 / 128), 256, 0, stream>>>(
        (const bf16_t*)hidden, Hc, Wt_attn,
        (const bf16_t*)b_attn, bb_attn, qkv, 4096, 3072, 1024, 1, det);

    attn_mfma<<<dim3(SEQ_T / 64, NHEAD, 2), 256, 0, stream>>>(qkv, attn_o);

    gemm_bt_bias<64><<<dim3(1024 / 64, 4096 / 128), 256, 0, stream>>>(
        attn_o, attn_o, Wt_proj,
        (const bf16_t*)b_proj, bb_proj, (void*)d_out, 4096, 1024, 1024, 0, det);
}